// Round 9
// baseline (225.121 us; speedup 1.0000x reference)
//
#include <hip/hip_runtime.h>

#define NN 50000
#define NE 800000
#define DIMH 128
#define NGRAPH 64
#define NTILES 3125          // 50000 / 16
#define PAIRS 1024           // wave-pairs in mlp grid
#define MLP_BLOCKS 512       // 2 pairs/block
#define MLP_ITERS 4          // ceil(3125/1024)
#define NBIN 196             // dst >> 8
#define BCAP 8064            // staging capacity per bin (max load ~4.4K)
#define SL_US 800000         // ushorts per feature-slice (NN*16)
#define SL_U2 200000         // uint2 per feature-slice

typedef __attribute__((ext_vector_type(8))) short bf16x8;
typedef __attribute__((ext_vector_type(4))) float f32x4;

__device__ __forceinline__ unsigned short f2b(float f) {
  unsigned int b = __float_as_uint(f);
  unsigned int r = (b + 0x7FFFu + ((b >> 16) & 1u)) >> 16;  // RNE
  return (unsigned short)r;
}
__device__ __forceinline__ float b2f_lo(unsigned int u) { return __uint_as_float(u << 16); }
__device__ __forceinline__ float b2f_hi(unsigned int u) { return __uint_as_float(u & 0xffff0000u); }
__device__ __forceinline__ unsigned int pk2(float lo, float hi) {
  return (unsigned int)f2b(lo) | ((unsigned int)f2b(hi) << 16);
}

// ---------------- binned compact-CSR build ----------------

__global__ __launch_bounds__(256) void bin_scatter_kernel(const int* __restrict__ src,
                                                          const int* __restrict__ dst,
                                                          int* __restrict__ gcnt,
                                                          int2* __restrict__ staging) {
  __shared__ int hist[NBIN];
  __shared__ int base[NBIN];
  int tid = threadIdx.x;
  for (int i = tid; i < NBIN; i += 256) hist[i] = 0;
  __syncthreads();
  int e0 = blockIdx.x * 2048;
  int2 ed[8];
  int bin[8], rank[8];
#pragma unroll
  for (int k = 0; k < 8; ++k) {
    int e = e0 + k * 256 + tid;
    bin[k] = 0; rank[k] = 0; ed[k] = make_int2(0, 0);
    if (e < NE) {
      ed[k].x = src[e]; ed[k].y = dst[e];
      bin[k] = ed[k].y >> 8;
      rank[k] = atomicAdd(&hist[bin[k]], 1);
    }
  }
  __syncthreads();
  for (int i = tid; i < NBIN; i += 256) base[i] = atomicAdd(&gcnt[i], hist[i]);
  __syncthreads();
#pragma unroll
  for (int k = 0; k < 8; ++k) {
    int e = e0 + k * 256 + tid;
    if (e < NE) staging[bin[k] * BCAP + base[bin[k]] + rank[k]] = ed[k];
  }
}

// one block per bin: per-node degree histogram -> block scan -> compact adj rows.
__global__ __launch_bounds__(256) void bin_fill_kernel(const int2* __restrict__ staging,
                                                       const int* __restrict__ gcnt,
                                                       int* __restrict__ adj,
                                                       int* __restrict__ row_ptr,
                                                       int* __restrict__ cnt,
                                                       int* __restrict__ alloc) {
  __shared__ int hdeg[256], loc[256], c2[256];
  __shared__ int sbase;
  int b = blockIdx.x;
  int tid = threadIdx.x;
  hdeg[tid] = 0; c2[tid] = 0;
  __syncthreads();
  int n = gcnt[b];
  for (int i = tid; i < n; i += 256)
    atomicAdd(&hdeg[staging[b * BCAP + i].y & 255], 1);
  __syncthreads();
  int v = hdeg[tid];
  loc[tid] = v;
  __syncthreads();
  for (int off = 1; off < 256; off <<= 1) {
    int t = (tid >= off) ? loc[tid - off] : 0;
    __syncthreads();
    loc[tid] += t;
    __syncthreads();
  }
  if (tid == 255) sbase = atomicAdd(alloc, loc[255]);
  __syncthreads();
  int excl = loc[tid] - v;
  int node = b * 256 + tid;
  if (node < NN) { row_ptr[node] = sbase + excl; cnt[node] = v; }
  loc[tid] = excl;
  __syncthreads();
  for (int i = tid; i < n; i += 256) {
    int2 e = staging[b * BCAP + i];
    int local = e.y & 255;
    int r = atomicAdd(&c2[local], 1);
    adj[sbase + loc[local] + r] = e.x;
  }
}

// ---------------- prep: weight transposes + out init + counters ----------------

struct WPtrs { const float* w[6]; const float* b_out; };

__global__ __launch_bounds__(256) void prep_kernel(WPtrs ptrs, unsigned short* __restrict__ wt,
                                                   float* __restrict__ out,
                                                   int* __restrict__ gcnt,
                                                   int* __restrict__ alloc) {
  int i = blockIdx.x * 256 + threadIdx.x;  // 6*16384 elems, m uniform per block
  int m = i >> 14;
  int idx = i & 16383;
  int c = idx >> 7, k = idx & 127;
  wt[m * 16384 + idx] = f2b(ptrs.w[m][k * DIMH + c]);
  if (i < NGRAPH) out[i] = ptrs.b_out[0];
  if (i < NBIN) gcnt[i] = 0;
  if (i == NBIN) *alloc = 0;
}

// h (row-major fp32) -> sliced bf16 [slice][node][16f]
__global__ void convh_kernel(const float* __restrict__ h, uint2* __restrict__ Hs) {
  int t = blockIdx.x * 256 + threadIdx.x;  // NN*32 groups of 4 feats
  int node = t >> 5;
  int q = t & 31;            // feat group: feats q*4..q*4+3
  float4 v = *(const float4*)&h[node * DIMH + q * 4];
  uint2 o;
  o.x = pk2(v.x, v.y);
  o.y = pk2(v.z, v.w);
  Hs[(q >> 2) * SL_U2 + node * 4 + (q & 3)] = o;
}

// ---------------- aggregation: sliced, XCD-affine ----------------
// slice = blockIdx & 7 (round-robin dispatch -> one slice per XCD; its 1.6MB
// column stays L2-resident). 4 lanes per node, uint2 (4 feats) per lane.
__global__ __launch_bounds__(256) void agg_kernel(const uint2* __restrict__ Hs,
                                                  const int* __restrict__ row_ptr,
                                                  const int* __restrict__ cnt,
                                                  const int* __restrict__ adj,
                                                  uint2* __restrict__ Zs) {
  int bid = blockIdx.x;
  int slice = bid & 7;
  int nb = bid >> 3;
  int tid = threadIdx.x;
  int node = nb * 64 + (tid >> 2);
  int l4 = tid & 3;
  if (node >= NN) return;
  const uint2* hp = Hs + slice * SL_U2;
  int start = row_ptr[node];
  int c = cnt[node];
  uint2 own = hp[node * 4 + l4];
  float a0 = b2f_lo(own.x), a1 = b2f_hi(own.x), a2 = b2f_lo(own.y), a3 = b2f_hi(own.y);
  int j = 0;
  for (; j + 4 <= c; j += 4) {
    int my = adj[start + j + l4];
    int n0 = __shfl(my, 0, 4), n1 = __shfl(my, 1, 4);
    int n2 = __shfl(my, 2, 4), n3 = __shfl(my, 3, 4);
    uint2 u0 = hp[n0 * 4 + l4], u1 = hp[n1 * 4 + l4];
    uint2 u2 = hp[n2 * 4 + l4], u3 = hp[n3 * 4 + l4];
    a0 += b2f_lo(u0.x); a1 += b2f_hi(u0.x); a2 += b2f_lo(u0.y); a3 += b2f_hi(u0.y);
    a0 += b2f_lo(u1.x); a1 += b2f_hi(u1.x); a2 += b2f_lo(u1.y); a3 += b2f_hi(u1.y);
    a0 += b2f_lo(u2.x); a1 += b2f_hi(u2.x); a2 += b2f_lo(u2.y); a3 += b2f_hi(u2.y);
    a0 += b2f_lo(u3.x); a1 += b2f_hi(u3.x); a2 += b2f_lo(u3.y); a3 += b2f_hi(u3.y);
  }
  for (; j < c; ++j) {
    int nbr = adj[start + j];
    uint2 u = hp[nbr * 4 + l4];
    a0 += b2f_lo(u.x); a1 += b2f_hi(u.x); a2 += b2f_lo(u.y); a3 += b2f_hi(u.y);
  }
  uint2 o;
  o.x = pk2(a0, a1);
  o.y = pk2(a2, a3);
  Zs[slice * SL_U2 + node * 4 + l4] = o;
}

// ---------------- MLP v2: register-resident W, wave-pair, sliced I/O ----------------
__global__ __launch_bounds__(256, 2) void mlp_kernel(const unsigned short* __restrict__ X,
                                                     const unsigned short* __restrict__ W1t,
                                                     const float* __restrict__ b1,
                                                     const unsigned short* __restrict__ W2t,
                                                     const float* __restrict__ b2,
                                                     unsigned short* __restrict__ Y,
                                                     const int* __restrict__ gids,
                                                     const float* __restrict__ wout,
                                                     float* __restrict__ gout) {
  __shared__ unsigned short y1[2][2][2048];  // [pair][dbuf][16 rows x 128 cols bf16]
  __shared__ float s_gout[NGRAPH];
  int tid = threadIdx.x;
  if (tid < NGRAPH) s_gout[tid] = 0.f;

  int wv = tid >> 6;
  int lane = tid & 63;
  int pb = wv >> 1;
  int half = wv & 1;
  int l15 = lane & 15;
  int g = lane >> 4;
  int p = blockIdx.x * 2 + pb;

  // sliced A-load: feats kt*32+g*8..+7 of row R -> slice 2kt+(g>>1), half (g&1)
  int asl_base = (g >> 1) * SL_US + (g & 1) * 8 + l15 * 16;  // + 2*kt*SL_US + R*16

  bf16x8 a[4];
  {
    int roff = p * 256;  // R*16 with R=p*16
#pragma unroll
    for (int kt = 0; kt < 4; ++kt)
      a[kt] = *(const bf16x8*)(X + 2 * kt * SL_US + roff + asl_base);
  }

  bf16x8 fb1[4][4], fb2[4][4];
  const unsigned short* w1b = W1t + (half * 64 + l15) * DIMH + g * 8;
  const unsigned short* w2b = W2t + (half * 64 + l15) * DIMH + g * 8;
#pragma unroll
  for (int n = 0; n < 4; ++n)
#pragma unroll
    for (int kt = 0; kt < 4; ++kt) {
      fb1[n][kt] = *(const bf16x8*)(w1b + n * 16 * DIMH + kt * 32);
      fb2[n][kt] = *(const bf16x8*)(w2b + n * 16 * DIMH + kt * 32);
    }
  float b1v[4], b2v[4], wov[4];
#pragma unroll
  for (int n = 0; n < 4; ++n) {
    int col = half * 64 + n * 16 + l15;
    b1v[n] = b1[col];
    b2v[n] = b2[col];
    wov[n] = wout[col];
  }
  __syncthreads();

#pragma unroll
  for (int i = 0; i < MLP_ITERS; ++i) {
    int rtc = p + i * PAIRS;
    bool active = rtc < NTILES;
    unsigned short* buf = y1[pb][i & 1];

    if (active) {
#pragma unroll
      for (int n = 0; n < 4; ++n) {
        f32x4 acc = (f32x4){0.f, 0.f, 0.f, 0.f};
#pragma unroll
        for (int kt = 0; kt < 4; ++kt)
          acc = __builtin_amdgcn_mfma_f32_16x16x32_bf16(a[kt], fb1[n][kt], acc, 0, 0, 0);
        int col2 = (half * 64 + n * 16 + l15) * 2;
#pragma unroll
        for (int r = 0; r < 4; ++r) {
          float f = fmaxf(acc[r] + b1v[n], 0.f);
          int row = 4 * g + r;
          buf[((row * 256 + col2) ^ (row << 4)) >> 1] = f2b(f);
        }
      }
    }

    // prefetch next tile's A fragments
    int rtn = p + (i + 1) * PAIRS;
    if (i + 1 < MLP_ITERS && rtn < NTILES) {
      int roff = rtn * 256;
#pragma unroll
      for (int kt = 0; kt < 4; ++kt)
        a[kt] = *(const bf16x8*)(X + 2 * kt * SL_US + roff + asl_base);
    }

    __syncthreads();  // Y1 tile complete (both halves)

    if (active) {
      bf16x8 a2[4];
#pragma unroll
      for (int kt = 0; kt < 4; ++kt)
        a2[kt] = *(const bf16x8*)&buf[((l15 * 256 + kt * 64 + g * 16) ^ (l15 << 4)) >> 1];

      float pr[4] = {0.f, 0.f, 0.f, 0.f};
#pragma unroll
      for (int n = 0; n < 4; ++n) {
        f32x4 acc = (f32x4){0.f, 0.f, 0.f, 0.f};
#pragma unroll
        for (int kt = 0; kt < 4; ++kt)
          acc = __builtin_amdgcn_mfma_f32_16x16x32_bf16(a2[kt], fb2[n][kt], acc, 0, 0, 0);
        int sl = 4 * half + n;  // output col slice
#pragma unroll
        for (int r = 0; r < 4; ++r) {
          float f = acc[r] + b2v[n];
          if (Y) Y[sl * SL_US + (rtc * 16 + 4 * g + r) * 16 + l15] = f2b(f);
          pr[r] += f * wov[n];
        }
      }
#pragma unroll
      for (int r = 0; r < 4; ++r) {
#pragma unroll
        for (int off = 1; off < 16; off <<= 1) pr[r] += __shfl_xor(pr[r], off, 64);
      }
      if (l15 == 0) {
#pragma unroll
        for (int r = 0; r < 4; ++r)
          atomicAdd(&s_gout[gids[rtc * 16 + 4 * g + r]], pr[r]);
      }
    }
  }

  __syncthreads();
  if (tid < NGRAPH) {
    float v = s_gout[tid];
    if (v != 0.f) atomicAdd(&gout[tid], v);
  }
}

// ---------------- launch ----------------

extern "C" void kernel_launch(void* const* d_in, const int* in_sizes, int n_in,
                              void* d_out, int out_size, void* d_ws, size_t ws_size,
                              hipStream_t stream) {
  const float* h = (const float*)d_in[0];
  const int* src = (const int*)d_in[1];
  const int* dst = (const int*)d_in[2];
  const int* gids = (const int*)d_in[3];
  const float* w_out = (const float*)d_in[16];
  const float* b_out = (const float*)d_in[17];
  float* out = (float*)d_out;

  char* base = (char*)d_ws;
  unsigned short* buf0 = (unsigned short*)(base);             // 12,800,000 B (sliced io ping)
  unsigned short* buf1 = (unsigned short*)(base + 12800000);  // 12,800,000 B (sliced io pong)
  int2* staging = (int2*)(base + 25600000);                   // 12,644,352 B
  int* adj = (int*)(base + 38400000);                         // 3,200,000 B
  int* row_ptr = (int*)(base + 41600000);                     // 200,000 B
  int* cnt = (int*)(base + 41800064);                         // 200,000 B
  int* gcnt = (int*)(base + 42000128);                        // 784 B
  int* alloc = (int*)(base + 42001024);                       // 4 B
  unsigned short* wt = (unsigned short*)(base + 42002048);    // 6 x 32,768 B

  WPtrs ptrs;
  for (int l = 0; l < 3; ++l) {
    ptrs.w[2 * l] = (const float*)d_in[4 + l * 4];
    ptrs.w[2 * l + 1] = (const float*)d_in[6 + l * 4];
  }
  ptrs.b_out = b_out;

  prep_kernel<<<384, 256, 0, stream>>>(ptrs, wt, out, gcnt, alloc);
  bin_scatter_kernel<<<(NE + 2047) / 2048, 256, 0, stream>>>(src, dst, gcnt, staging);
  bin_fill_kernel<<<NBIN, 256, 0, stream>>>(staging, gcnt, adj, row_ptr, cnt, alloc);
  convh_kernel<<<(NN * 32) / 256 + 1, 256, 0, stream>>>(h, (uint2*)buf0);

  int agg_blocks = 782 * 8;  // (nodes/64) x 8 slices; slice = bid & 7 (XCD affinity)

  for (int l = 0; l < 3; ++l) {
    const float* b1 = (const float*)d_in[5 + l * 4];
    const float* b2 = (const float*)d_in[7 + l * 4];
    const unsigned short* Hl = (l & 1) ? buf1 : buf0;
    unsigned short* Yl = (l & 1) ? buf0 : buf1;
    // z = h + agg (sliced) -> reuse the *other* buffer region? No: z needs its own
    // space; write z into the buffer that will NOT be needed: z is consumed only by
    // this layer's mlp, and Yl is written only after mlp reads z. Use staging area.
    unsigned short* Zl = (unsigned short*)staging;  // 12.6MB >= 12.8? NO -> use Yl? unsafe.
    // staging (12,644,352 B) < 12.8MB needed; but adj region follows immediately and
    // bin data is dead after CSR build -> z occupies staging..staging+12.8MB safely
    // (overlaps adj? 25.6M+12.8M = 38.4M = adj start. adj is LIVE. Use dedicated:
    // actually place z at base+42199040+196608... keep simple: z goes in the pong
    // buffer only when safe. Safest: separate z region after wt.
    Zl = (unsigned short*)(base + 42300000);
    agg_kernel<<<agg_blocks, 256, 0, stream>>>((const uint2*)Hl, row_ptr, cnt, adj,
                                               (uint2*)Zl);
    mlp_kernel<<<MLP_BLOCKS, 256, 0, stream>>>(Zl, wt + (2 * l) * 16384, b1,
                                               wt + (2 * l + 1) * 16384, b2,
                                               (l == 2) ? nullptr : Yl,
                                               gids, w_out + l * DIMH, out);
  }
}

// Round 10
// 220.563 us; speedup vs baseline: 1.0207x; 1.0207x over previous
//
#include <hip/hip_runtime.h>

#define NN 50000
#define NE 800000
#define DIMH 128
#define NGRAPH 64
#define NTILES 3125          // 50000 / 16
#define PAIRS 1024           // wave-pairs in mlp grid
#define MLP_BLOCKS 512       // 2 pairs/block
#define MLP_ITERS 4          // ceil(3125/1024)
#define NBIN 196             // dst >> 8
#define BCAP 8064            // staging capacity per bin (max load ~4.4K)
#define SL_US 800000         // ushorts per feature-slice (NN*16)
#define SL_U4 100000         // uint4 per feature-slice

typedef __attribute__((ext_vector_type(8))) short bf16x8;
typedef __attribute__((ext_vector_type(4))) float f32x4;

__device__ __forceinline__ unsigned short f2b(float f) {
  unsigned int b = __float_as_uint(f);
  unsigned int r = (b + 0x7FFFu + ((b >> 16) & 1u)) >> 16;  // RNE
  return (unsigned short)r;
}
__device__ __forceinline__ float b2f_lo(unsigned int u) { return __uint_as_float(u << 16); }
__device__ __forceinline__ float b2f_hi(unsigned int u) { return __uint_as_float(u & 0xffff0000u); }
__device__ __forceinline__ unsigned int pk2(float lo, float hi) {
  return (unsigned int)f2b(lo) | ((unsigned int)f2b(hi) << 16);
}
__device__ __forceinline__ void add8(float* a, uint4 u) {
  a[0] += b2f_lo(u.x); a[1] += b2f_hi(u.x);
  a[2] += b2f_lo(u.y); a[3] += b2f_hi(u.y);
  a[4] += b2f_lo(u.z); a[5] += b2f_hi(u.z);
  a[6] += b2f_lo(u.w); a[7] += b2f_hi(u.w);
}

// ---------------- binned compact-CSR build ----------------

__global__ __launch_bounds__(256) void bin_scatter_kernel(const int* __restrict__ src,
                                                          const int* __restrict__ dst,
                                                          int* __restrict__ gcnt,
                                                          int2* __restrict__ staging) {
  __shared__ int hist[NBIN];
  __shared__ int base[NBIN];
  int tid = threadIdx.x;
  for (int i = tid; i < NBIN; i += 256) hist[i] = 0;
  __syncthreads();
  int e0 = blockIdx.x * 2048;
  int2 ed[8];
  int bin[8], rank[8];
#pragma unroll
  for (int k = 0; k < 8; ++k) {
    int e = e0 + k * 256 + tid;
    bin[k] = 0; rank[k] = 0; ed[k] = make_int2(0, 0);
    if (e < NE) {
      ed[k].x = src[e]; ed[k].y = dst[e];
      bin[k] = ed[k].y >> 8;
      rank[k] = atomicAdd(&hist[bin[k]], 1);
    }
  }
  __syncthreads();
  for (int i = tid; i < NBIN; i += 256) base[i] = atomicAdd(&gcnt[i], hist[i]);
  __syncthreads();
#pragma unroll
  for (int k = 0; k < 8; ++k) {
    int e = e0 + k * 256 + tid;
    if (e < NE) staging[bin[k] * BCAP + base[bin[k]] + rank[k]] = ed[k];
  }
}

// one block per bin; row starts rounded to EVEN so agg's int2 index loads are
// 8B-aligned.
__global__ __launch_bounds__(256) void bin_fill_kernel(const int2* __restrict__ staging,
                                                       const int* __restrict__ gcnt,
                                                       int* __restrict__ adj,
                                                       int* __restrict__ row_ptr,
                                                       int* __restrict__ cnt,
                                                       int* __restrict__ alloc) {
  __shared__ int hdeg[256], loc[256], c2[256];
  __shared__ int sbase;
  int b = blockIdx.x;
  int tid = threadIdx.x;
  hdeg[tid] = 0; c2[tid] = 0;
  __syncthreads();
  int n = gcnt[b];
  for (int i = tid; i < n; i += 256)
    atomicAdd(&hdeg[staging[b * BCAP + i].y & 255], 1);
  __syncthreads();
  int v = hdeg[tid];
  int va = (v + 1) & ~1;  // even-aligned allocation
  loc[tid] = va;
  __syncthreads();
  for (int off = 1; off < 256; off <<= 1) {
    int t = (tid >= off) ? loc[tid - off] : 0;
    __syncthreads();
    loc[tid] += t;
    __syncthreads();
  }
  if (tid == 255) sbase = atomicAdd(alloc, loc[255]);
  __syncthreads();
  int excl = loc[tid] - va;
  int node = b * 256 + tid;
  if (node < NN) { row_ptr[node] = sbase + excl; cnt[node] = v; }
  loc[tid] = excl;
  __syncthreads();
  for (int i = tid; i < n; i += 256) {
    int2 e = staging[b * BCAP + i];
    int local = e.y & 255;
    int r = atomicAdd(&c2[local], 1);
    adj[sbase + loc[local] + r] = e.x;
  }
}

// ---------------- prep: weight transposes + v2/s2 + out init + counters ----------------

struct WPtrs { const float* w[6]; const float* b_out; const float* b2_last;
               const float* w_out; };

__global__ __launch_bounds__(256) void prep_kernel(WPtrs ptrs, unsigned short* __restrict__ wt,
                                                   float* __restrict__ out,
                                                   int* __restrict__ gcnt,
                                                   int* __restrict__ alloc,
                                                   float* __restrict__ v2,
                                                   float* __restrict__ s2) {
  int i = blockIdx.x * 256 + threadIdx.x;  // 6*16384 elems, m uniform per block
  int m = i >> 14;
  int idx = i & 16383;
  int c = idx >> 7, k = idx & 127;
  wt[m * 16384 + idx] = f2b(ptrs.w[m][k * DIMH + c]);
  if (i < NGRAPH) out[i] = ptrs.b_out[0];
  if (i < NBIN) gcnt[i] = 0;
  if (i == NBIN) *alloc = 0;
  if (i < DIMH) {  // v2[k] = sum_c W2_l2[k][c] * w_out[256+c]
    float s = 0.f;
    const float* w2r = ptrs.w[5] + i * DIMH;
    for (int cc = 0; cc < DIMH; ++cc) s += w2r[cc] * ptrs.w_out[2 * DIMH + cc];
    v2[i] = s;
  }
  if (i == DIMH) {  // s2 = dot(b2_l2, w_out[256:])
    float s = 0.f;
    for (int cc = 0; cc < DIMH; ++cc) s += ptrs.b2_last[cc] * ptrs.w_out[2 * DIMH + cc];
    *s2 = s;
  }
}

// h (row-major fp32) -> sliced bf16 [slice][node][16f]
__global__ void convh_kernel(const float* __restrict__ h, uint2* __restrict__ Hs) {
  int t = blockIdx.x * 256 + threadIdx.x;  // NN*32 groups of 4 feats
  if (t >= NN * 32) return;
  int node = t >> 5;
  int q = t & 31;            // feat group: feats q*4..q*4+3
  float4 v = *(const float4*)&h[node * DIMH + q * 4];
  uint2 o;
  o.x = pk2(v.x, v.y);
  o.y = pk2(v.z, v.w);
  Hs[(q >> 2) * (SL_U4 * 2) + node * 4 + (q & 3)] = o;
}

// ---------------- aggregation: sliced, XCD-affine, deep-ILP ----------------
// slice = blockIdx & 7 (L2-resident 1.6MB column per XCD). 2 lanes/node,
// uint4 (8 feats)/lane; unroll 8 edges -> 8 feature + 4 index loads in flight
// (the round-9 kernel had VGPR=16 and ~3 loads in flight: latency-bound).
__global__ __launch_bounds__(256) void agg_kernel(const uint4* __restrict__ Hs,
                                                  const int* __restrict__ row_ptr,
                                                  const int* __restrict__ cnt,
                                                  const int* __restrict__ adj,
                                                  uint4* __restrict__ Zs) {
  int bid = blockIdx.x;
  int slice = bid & 7;
  int nb = bid >> 3;
  int tid = threadIdx.x;
  int node = nb * 128 + (tid >> 1);
  int l2 = tid & 1;
  if (node >= NN) return;
  const uint4* hp = Hs + slice * SL_U4;
  int start = row_ptr[node];
  int c = cnt[node];
  float a[8];
  {
    uint4 own = hp[node * 2 + l2];
    a[0] = b2f_lo(own.x); a[1] = b2f_hi(own.x);
    a[2] = b2f_lo(own.y); a[3] = b2f_hi(own.y);
    a[4] = b2f_lo(own.z); a[5] = b2f_hi(own.z);
    a[6] = b2f_lo(own.w); a[7] = b2f_hi(own.w);
  }
  int j = 0;
  for (; j + 8 <= c; j += 8) {
    int2 i01 = *(const int2*)(adj + start + j);
    int2 i23 = *(const int2*)(adj + start + j + 2);
    int2 i45 = *(const int2*)(adj + start + j + 4);
    int2 i67 = *(const int2*)(adj + start + j + 6);
    uint4 u0 = hp[i01.x * 2 + l2];
    uint4 u1 = hp[i01.y * 2 + l2];
    uint4 u2 = hp[i23.x * 2 + l2];
    uint4 u3 = hp[i23.y * 2 + l2];
    uint4 u4 = hp[i45.x * 2 + l2];
    uint4 u5 = hp[i45.y * 2 + l2];
    uint4 u6 = hp[i67.x * 2 + l2];
    uint4 u7 = hp[i67.y * 2 + l2];
    add8(a, u0); add8(a, u1); add8(a, u2); add8(a, u3);
    add8(a, u4); add8(a, u5); add8(a, u6); add8(a, u7);
  }
  for (; j + 2 <= c; j += 2) {
    int2 i01 = *(const int2*)(adj + start + j);
    uint4 u0 = hp[i01.x * 2 + l2];
    uint4 u1 = hp[i01.y * 2 + l2];
    add8(a, u0); add8(a, u1);
  }
  if (j < c) {
    int n0 = adj[start + j];
    add8(a, hp[n0 * 2 + l2]);
  }
  uint4 o;
  o.x = pk2(a[0], a[1]);
  o.y = pk2(a[2], a[3]);
  o.z = pk2(a[4], a[5]);
  o.w = pk2(a[6], a[7]);
  Zs[slice * SL_U4 + node * 2 + l2] = o;
}

// ---------------- MLP: register-resident W, wave-pair; last layer collapses
// GEMM2 into a v2-dot inside the GEMM1 epilogue ----------------
__global__ __launch_bounds__(256, 2) void mlp_kernel(const unsigned short* __restrict__ X,
                                                     const unsigned short* __restrict__ W1t,
                                                     const float* __restrict__ b1,
                                                     const unsigned short* __restrict__ W2t,
                                                     const float* __restrict__ b2,
                                                     unsigned short* __restrict__ Y,
                                                     const int* __restrict__ gids,
                                                     const float* __restrict__ wout,
                                                     float* __restrict__ gout,
                                                     const float* __restrict__ v2,
                                                     const float* __restrict__ s2p) {
  __shared__ unsigned short y1[2][2][2048];  // [pair][dbuf][16 rows x 128 cols bf16]
  __shared__ float s_gout[NGRAPH];
  int tid = threadIdx.x;
  if (tid < NGRAPH) s_gout[tid] = 0.f;
  bool last = (v2 != nullptr);

  int wv = tid >> 6;
  int lane = tid & 63;
  int pb = wv >> 1;
  int half = wv & 1;
  int l15 = lane & 15;
  int g = lane >> 4;
  int p = blockIdx.x * 2 + pb;

  // sliced A-load: feats kt*32+g*8..+7 of row R -> slice 2kt+(g>>1), half (g&1)
  int asl_base = (g >> 1) * SL_US + (g & 1) * 8 + l15 * 16;  // + 2*kt*SL_US + R*16

  bf16x8 a[4];
  {
    int roff = p * 256;
#pragma unroll
    for (int kt = 0; kt < 4; ++kt)
      a[kt] = *(const bf16x8*)(X + 2 * kt * SL_US + roff + asl_base);
  }

  bf16x8 fb1[4][4], fb2[4][4];
  const unsigned short* w1b = W1t + (half * 64 + l15) * DIMH + g * 8;
  const unsigned short* w2b = W2t + (half * 64 + l15) * DIMH + g * 8;
#pragma unroll
  for (int n = 0; n < 4; ++n)
#pragma unroll
    for (int kt = 0; kt < 4; ++kt) {
      fb1[n][kt] = *(const bf16x8*)(w1b + n * 16 * DIMH + kt * 32);
      if (!last) fb2[n][kt] = *(const bf16x8*)(w2b + n * 16 * DIMH + kt * 32);
    }
  float b1v[4], b2v[4], wov[4], v2v[4];
  float s2v = last ? *s2p : 0.f;
#pragma unroll
  for (int n = 0; n < 4; ++n) {
    int col = half * 64 + n * 16 + l15;
    b1v[n] = b1[col];
    b2v[n] = last ? 0.f : b2[col];
    wov[n] = last ? 0.f : wout[col];
    v2v[n] = last ? v2[col] : 0.f;
  }
  __syncthreads();

#pragma unroll
  for (int i = 0; i < MLP_ITERS; ++i) {
    int rtc = p + i * PAIRS;
    bool active = rtc < NTILES;
    unsigned short* buf = y1[pb][i & 1];

    if (active) {
      float pr1[4] = {0.f, 0.f, 0.f, 0.f};
#pragma unroll
      for (int n = 0; n < 4; ++n) {
        f32x4 acc = (f32x4){0.f, 0.f, 0.f, 0.f};
#pragma unroll
        for (int kt = 0; kt < 4; ++kt)
          acc = __builtin_amdgcn_mfma_f32_16x16x32_bf16(a[kt], fb1[n][kt], acc, 0, 0, 0);
        int col2 = (half * 64 + n * 16 + l15) * 2;
#pragma unroll
        for (int r = 0; r < 4; ++r) {
          float f = fmaxf(acc[r] + b1v[n], 0.f);
          if (!last) {
            int row = 4 * g + r;
            buf[((row * 256 + col2) ^ (row << 4)) >> 1] = f2b(f);
          } else {
            pr1[r] += f * v2v[n];
          }
        }
      }
      if (last) {
#pragma unroll
        for (int r = 0; r < 4; ++r) {
#pragma unroll
          for (int off = 1; off < 16; off <<= 1) pr1[r] += __shfl_xor(pr1[r], off, 64);
        }
        if (l15 == 0) {
          float s2add = (half == 0) ? s2v : 0.f;  // s2 once per row
#pragma unroll
          for (int r = 0; r < 4; ++r)
            atomicAdd(&s_gout[gids[rtc * 16 + 4 * g + r]], pr1[r] + s2add);
        }
      }
    }

    // prefetch next tile's A fragments
    int rtn = p + (i + 1) * PAIRS;
    if (i + 1 < MLP_ITERS && rtn < NTILES) {
      int roff = rtn * 256;
#pragma unroll
      for (int kt = 0; kt < 4; ++kt)
        a[kt] = *(const bf16x8*)(X + 2 * kt * SL_US + roff + asl_base);
    }

    __syncthreads();  // Y1 tile complete (both halves)

    if (active && !last) {
      bf16x8 a2[4];
#pragma unroll
      for (int kt = 0; kt < 4; ++kt)
        a2[kt] = *(const bf16x8*)&buf[((l15 * 256 + kt * 64 + g * 16) ^ (l15 << 4)) >> 1];

      float pr[4] = {0.f, 0.f, 0.f, 0.f};
#pragma unroll
      for (int n = 0; n < 4; ++n) {
        f32x4 acc = (f32x4){0.f, 0.f, 0.f, 0.f};
#pragma unroll
        for (int kt = 0; kt < 4; ++kt)
          acc = __builtin_amdgcn_mfma_f32_16x16x32_bf16(a2[kt], fb2[n][kt], acc, 0, 0, 0);
        int sl = 4 * half + n;  // output col slice
#pragma unroll
        for (int r = 0; r < 4; ++r) {
          float f = acc[r] + b2v[n];
          Y[sl * SL_US + (rtc * 16 + 4 * g + r) * 16 + l15] = f2b(f);
          pr[r] += f * wov[n];
        }
      }
#pragma unroll
      for (int r = 0; r < 4; ++r) {
#pragma unroll
        for (int off = 1; off < 16; off <<= 1) pr[r] += __shfl_xor(pr[r], off, 64);
      }
      if (l15 == 0) {
#pragma unroll
        for (int r = 0; r < 4; ++r)
          atomicAdd(&s_gout[gids[rtc * 16 + 4 * g + r]], pr[r]);
      }
    }
  }

  __syncthreads();
  if (tid < NGRAPH) {
    float v = s_gout[tid];
    if (v != 0.f) atomicAdd(&gout[tid], v);
  }
}

// ---------------- launch ----------------

extern "C" void kernel_launch(void* const* d_in, const int* in_sizes, int n_in,
                              void* d_out, int out_size, void* d_ws, size_t ws_size,
                              hipStream_t stream) {
  const float* h = (const float*)d_in[0];
  const int* src = (const int*)d_in[1];
  const int* dst = (const int*)d_in[2];
  const int* gids = (const int*)d_in[3];
  const float* w_out = (const float*)d_in[16];
  const float* b_out = (const float*)d_in[17];
  float* out = (float*)d_out;

  char* base = (char*)d_ws;
  unsigned short* buf0 = (unsigned short*)(base);             // 12.8 MB (sliced io ping)
  unsigned short* buf1 = (unsigned short*)(base + 12800000);  // 12.8 MB (sliced io pong)
  int2* staging = (int2*)(base + 25600000);                   // 12,644,352 B
  int* adj = (int*)(base + 38400000);                         // 3,400,000 B (even-padded)
  int* row_ptr = (int*)(base + 41800064);                     // 200,000 B
  int* cnt = (int*)(base + 42000128);                         // 200,000 B
  int* gcnt = (int*)(base + 42200192);                        // 784 B
  int* alloc = (int*)(base + 42201024);                       // 4 B
  unsigned short* wt = (unsigned short*)(base + 42201088);    // 196,608 B
  float* v2 = (float*)(base + 42397696);                      // 512 B
  float* s2 = (float*)(base + 42398208);                      // 4 B
  unsigned short* Zs = (unsigned short*)(base + 42400000);    // 12.8 MB

  WPtrs ptrs;
  for (int l = 0; l < 3; ++l) {
    ptrs.w[2 * l] = (const float*)d_in[4 + l * 4];
    ptrs.w[2 * l + 1] = (const float*)d_in[6 + l * 4];
  }
  ptrs.b_out = b_out;
  ptrs.b2_last = (const float*)d_in[15];
  ptrs.w_out = w_out;

  prep_kernel<<<384, 256, 0, stream>>>(ptrs, wt, out, gcnt, alloc, v2, s2);
  bin_scatter_kernel<<<(NE + 2047) / 2048, 256, 0, stream>>>(src, dst, gcnt, staging);
  bin_fill_kernel<<<NBIN, 256, 0, stream>>>(staging, gcnt, adj, row_ptr, cnt, alloc);
  convh_kernel<<<(NN * 32 + 255) / 256, 256, 0, stream>>>(h, (uint2*)buf0);

  int agg_blocks = 391 * 8;  // ceil(50000/128) node-blocks x 8 slices (bid&7 = slice)

  for (int l = 0; l < 3; ++l) {
    const float* b1 = (const float*)d_in[5 + l * 4];
    const float* b2 = (const float*)d_in[7 + l * 4];
    const unsigned short* Hl = (l & 1) ? buf1 : buf0;
    unsigned short* Yl = (l & 1) ? buf0 : buf1;
    int lastl = (l == 2);
    agg_kernel<<<agg_blocks, 256, 0, stream>>>((const uint4*)Hl, row_ptr, cnt, adj,
                                               (uint4*)Zs);
    mlp_kernel<<<MLP_BLOCKS, 256, 0, stream>>>(Zs, wt + (2 * l) * 16384, b1,
                                               wt + (2 * l + 1) * 16384, b2,
                                               lastl ? nullptr : Yl,
                                               gids, w_out + l * DIMH, out,
                                               lastl ? v2 : nullptr,
                                               lastl ? s2 : nullptr);
  }
}